// Round 6
// baseline (2387.118 us; speedup 1.0000x reference)
//
#include <hip/hip_runtime.h>
#include <math.h>

// ---------------------------------------------------------------------------
// TreeEncoder on MI355X.
// Factorization:
//   x_all = emb[wid];   z = sig(x@Wz_a + sum_h@Uz + bz)
//   r_ij  = sig(x_i@Wr + Ur_b + h_j@Ur)       -> Xr[wid_i] + u_j  (u precomputed)
//   pre_h = tanh(x@Wh_a + sum_gated@Uh + bh)
//   new_h = (1-z)*sum_h + z*pre_h ;  u_new = new_h@Ur
// Precompute over vocab V=1000: Xz, Xr, Xh, Xw  (includes biases).
// Per step t: gather(sum_h, sum_g) -> dual GEMM + GRU epilogue -> u GEMM.
// h rows live directly in d_out[0 : M*H]; root_vecs at d_out[M*H : ].
// ---------------------------------------------------------------------------

namespace {
constexpr int Hc    = 512;
constexpr int Vc    = 1000;
constexpr int Bc    = 512;
constexpr int NBc   = 8;
constexpr int Tc    = 6;
constexpr int Mc    = 86016;     // B * 2*(N-1) = 512*168
constexpr int EMAXc = 32768;
constexpr int BK    = 32;
}

__device__ __forceinline__ float sigm_(float x){ return 1.0f/(1.0f+expf(-x)); }

// ---------------- precompute X = emb @ W + bias  (A direct, bounds on rows) --
__global__ __launch_bounds__(256)
void k_gemm_bias(const float* __restrict__ A, const float* __restrict__ W,
                 const float* __restrict__ bias, float* __restrict__ C, int Mrows)
{
  __shared__ float As[BK][64];
  __shared__ float Bs[BK][64];
  const int tid  = threadIdx.x;
  const int row0 = blockIdx.x*64, col0 = blockIdx.y*64;
  const int ty = tid>>4, tx = tid&15;
  float acc[4][4] = {};
  for (int kt=0; kt<Hc; kt+=BK) {
#pragma unroll
    for (int i=0;i<2;i++){
      const int f  = tid + i*256;
      const int r  = f>>3, kg = f&7;
      const int gr = row0 + r;
      float4 a4 = make_float4(0.f,0.f,0.f,0.f);
      if (gr < Mrows) a4 = *(const float4*)&A[(size_t)gr*Hc + kt + kg*4];
      const float av_[4]={a4.x,a4.y,a4.z,a4.w};
#pragma unroll
      for (int j=0;j<4;j++){
        const int k = kg*4+j;
        As[k][r ^ ((k&7)<<2)] = av_[j];
      }
      const int kb = f>>4, cg = f&15;
      *(float4*)&Bs[kb][cg*4] = *(const float4*)&W[(size_t)(kt+kb)*Hc + col0 + cg*4];
    }
    __syncthreads();
#pragma unroll
    for (int k=0;k<BK;k++){
      const float4 av = *(const float4*)&As[k][(ty*4) ^ ((k&7)<<2)];
      const float4 bv = *(const float4*)&Bs[k][tx*4];
      const float aa[4]={av.x,av.y,av.z,av.w}, bb[4]={bv.x,bv.y,bv.z,bv.w};
#pragma unroll
      for (int i2=0;i2<4;i2++)
#pragma unroll
        for (int j2=0;j2<4;j2++)
          acc[i2][j2] = fmaf(aa[i2], bb[j2], acc[i2][j2]);
    }
    __syncthreads();
  }
  const int gc0 = col0 + tx*4;
  const float4 bv = *(const float4*)&bias[gc0];
  const float bb[4]={bv.x,bv.y,bv.z,bv.w};
#pragma unroll
  for (int i=0;i<4;i++){
    const int gr = row0 + ty*4 + i;
    if (gr >= Mrows) break;
    float4 o = make_float4(acc[i][0]+bb[0], acc[i][1]+bb[1],
                           acc[i][2]+bb[2], acc[i][3]+bb[3]);
    *(float4*)&C[(size_t)gr*Hc + gc0] = o;
  }
}

// ---------------- per-step gather: sum_h, sum_g -----------------------------
__global__ __launch_bounds__(256)
void k_gather_step(const int* __restrict__ ids, const int* __restrict__ msg_nei,
                   const int* __restrict__ msg_wid, const float* __restrict__ h,
                   const float* __restrict__ u, const float* __restrict__ Xr,
                   float* __restrict__ sumh, float* __restrict__ sumg)
{
  const int e  = blockIdx.x*2 + (threadIdx.x>>7);
  const int c0 = (threadIdx.x&127)<<2;
  const int idx = ids[e];
  float4 sh = make_float4(0.f,0.f,0.f,0.f);
  float4 sg = make_float4(0.f,0.f,0.f,0.f);
  if (idx < Mc) {
    const int wid = msg_wid[idx];
    const float4 xr = *(const float4*)&Xr[(size_t)wid*Hc + c0];
#pragma unroll
    for (int kk=0; kk<NBc; kk++){
      const int j = msg_nei[(size_t)idx*NBc + kk];
      if (j >= Mc) break;            // PAD tail
      const float4 hv = *(const float4*)&h[(size_t)j*Hc + c0];
      const float4 uv = *(const float4*)&u[(size_t)j*Hc + c0];
      sh.x += hv.x; sh.y += hv.y; sh.z += hv.z; sh.w += hv.w;
      sg.x += sigm_(xr.x+uv.x)*hv.x;
      sg.y += sigm_(xr.y+uv.y)*hv.y;
      sg.z += sigm_(xr.z+uv.z)*hv.z;
      sg.w += sigm_(xr.w+uv.w)*hv.w;
    }
  }
  *(float4*)&sumh[(size_t)e*Hc + c0] = sh;
  *(float4*)&sumg[(size_t)e*Hc + c0] = sg;
}

// ---------------- per-step dual GEMM + GRU epilogue -------------------------
__global__ __launch_bounds__(256)
void k_gemm_step(const float* __restrict__ sumh, const float* __restrict__ sumg,
                 const float* __restrict__ Uz, const float* __restrict__ Uh,
                 const float* __restrict__ Xz, const float* __restrict__ Xh,
                 const int* __restrict__ ids, const int* __restrict__ msg_wid,
                 float* __restrict__ hout)
{
  __shared__ float As1[BK][64], As2[BK][64];
  __shared__ float Bs1[BK][64], Bs2[BK][64];
  const int tid  = threadIdx.x;
  const int row0 = blockIdx.x*64, col0 = blockIdx.y*64;
  const int ty = tid>>4, tx = tid&15;
  float acc1[4][4] = {}, acc2[4][4] = {};
  for (int kt=0; kt<Hc; kt+=BK) {
#pragma unroll
    for (int i=0;i<2;i++){
      const int f  = tid + i*256;
      const int r  = f>>3, kg = f&7;
      const int gr = row0 + r;
      const float4 a1 = *(const float4*)&sumh[(size_t)gr*Hc + kt + kg*4];
      const float4 a2 = *(const float4*)&sumg[(size_t)gr*Hc + kt + kg*4];
      const float a1_[4]={a1.x,a1.y,a1.z,a1.w}, a2_[4]={a2.x,a2.y,a2.z,a2.w};
#pragma unroll
      for (int j=0;j<4;j++){
        const int k = kg*4+j;
        As1[k][r ^ ((k&7)<<2)] = a1_[j];
        As2[k][r ^ ((k&7)<<2)] = a2_[j];
      }
      const int kb = f>>4, cg = f&15;
      *(float4*)&Bs1[kb][cg*4] = *(const float4*)&Uz[(size_t)(kt+kb)*Hc + col0 + cg*4];
      *(float4*)&Bs2[kb][cg*4] = *(const float4*)&Uh[(size_t)(kt+kb)*Hc + col0 + cg*4];
    }
    __syncthreads();
#pragma unroll
    for (int k=0;k<BK;k++){
      const int ca = (ty*4) ^ ((k&7)<<2);
      const float4 av1 = *(const float4*)&As1[k][ca];
      const float4 av2 = *(const float4*)&As2[k][ca];
      const float4 bv1 = *(const float4*)&Bs1[k][tx*4];
      const float4 bv2 = *(const float4*)&Bs2[k][tx*4];
      const float a1_[4]={av1.x,av1.y,av1.z,av1.w}, b1_[4]={bv1.x,bv1.y,bv1.z,bv1.w};
      const float a2_[4]={av2.x,av2.y,av2.z,av2.w}, b2_[4]={bv2.x,bv2.y,bv2.z,bv2.w};
#pragma unroll
      for (int i2=0;i2<4;i2++)
#pragma unroll
        for (int j2=0;j2<4;j2++){
          acc1[i2][j2] = fmaf(a1_[i2], b1_[j2], acc1[i2][j2]);
          acc2[i2][j2] = fmaf(a2_[i2], b2_[j2], acc2[i2][j2]);
        }
    }
    __syncthreads();
  }
  const int gc0 = col0 + tx*4;
#pragma unroll
  for (int i=0;i<4;i++){
    const int gr  = row0 + ty*4 + i;
    const int idx = ids[gr];
    if (idx >= Mc) continue;         // DUMMY (never hit with exact E sizes)
    const int wid = msg_wid[idx];
    const float4 xz = *(const float4*)&Xz[(size_t)wid*Hc + gc0];
    const float4 xh = *(const float4*)&Xh[(size_t)wid*Hc + gc0];
    const float4 sh = *(const float4*)&sumh[(size_t)gr*Hc + gc0];
    const float xzv[4]={xz.x,xz.y,xz.z,xz.w};
    const float xhv[4]={xh.x,xh.y,xh.z,xh.w};
    const float shv[4]={sh.x,sh.y,sh.z,sh.w};
    float ov[4];
#pragma unroll
    for (int j=0;j<4;j++){
      const float z = sigm_(xzv[j] + acc1[i][j]);
      const float p = tanhf(xhv[j] + acc2[i][j]);
      ov[j] = (1.0f - z)*shv[j] + z*p;
    }
    float4 o = make_float4(ov[0],ov[1],ov[2],ov[3]);
    *(float4*)&hout[(size_t)idx*Hc + gc0] = o;
  }
}

// ---------------- per-step u = h[ids] @ Ur  (gathered A, scattered C) -------
__global__ __launch_bounds__(256)
void k_gemm_u(const float* __restrict__ h, const int* __restrict__ ids,
              const float* __restrict__ Ur, float* __restrict__ u)
{
  __shared__ float As[BK][64];
  __shared__ float Bs[BK][64];
  const int tid  = threadIdx.x;
  const int row0 = blockIdx.x*64, col0 = blockIdx.y*64;
  const int ty = tid>>4, tx = tid&15;
  const int r0 = tid>>3, kg = tid&7;
  const int idxA0 = ids[row0 + r0];
  const int idxA1 = ids[row0 + r0 + 32];
  float acc[4][4] = {};
  for (int kt=0; kt<Hc; kt+=BK) {
#pragma unroll
    for (int i=0;i<2;i++){
      const int r   = r0 + i*32;
      const int idx = i ? idxA1 : idxA0;
      float4 a4 = make_float4(0.f,0.f,0.f,0.f);
      if (idx < Mc) a4 = *(const float4*)&h[(size_t)idx*Hc + kt + kg*4];
      const float av_[4]={a4.x,a4.y,a4.z,a4.w};
#pragma unroll
      for (int j=0;j<4;j++){
        const int k = kg*4+j;
        As[k][r ^ ((k&7)<<2)] = av_[j];
      }
      const int f  = tid + i*256;
      const int kb = f>>4, cg = f&15;
      *(float4*)&Bs[kb][cg*4] = *(const float4*)&Ur[(size_t)(kt+kb)*Hc + col0 + cg*4];
    }
    __syncthreads();
#pragma unroll
    for (int k=0;k<BK;k++){
      const float4 av = *(const float4*)&As[k][(ty*4) ^ ((k&7)<<2)];
      const float4 bv = *(const float4*)&Bs[k][tx*4];
      const float aa[4]={av.x,av.y,av.z,av.w}, bb[4]={bv.x,bv.y,bv.z,bv.w};
#pragma unroll
      for (int i2=0;i2<4;i2++)
#pragma unroll
        for (int j2=0;j2<4;j2++)
          acc[i2][j2] = fmaf(aa[i2], bb[j2], acc[i2][j2]);
    }
    __syncthreads();
  }
  const int gc0 = col0 + tx*4;
#pragma unroll
  for (int i=0;i<4;i++){
    const int idx = ids[row0 + ty*4 + i];
    if (idx >= Mc) continue;
    float4 o = make_float4(acc[i][0],acc[i][1],acc[i][2],acc[i][3]);
    *(float4*)&u[(size_t)idx*Hc + gc0] = o;
  }
}

// ---------------- root gather + root GEMM -----------------------------------
__global__ __launch_bounds__(256)
void k_gather_root(const int* __restrict__ root_nei, const float* __restrict__ h,
                   float* __restrict__ sroot)
{
  const int b  = blockIdx.x*2 + (threadIdx.x>>7);
  const int c0 = (threadIdx.x&127)<<2;
  float4 s = make_float4(0.f,0.f,0.f,0.f);
#pragma unroll
  for (int kk=0; kk<NBc; kk++){
    const int j = root_nei[(size_t)b*NBc + kk];
    if (j >= Mc) break;
    const float4 hv = *(const float4*)&h[(size_t)j*Hc + c0];
    s.x+=hv.x; s.y+=hv.y; s.z+=hv.z; s.w+=hv.w;
  }
  *(float4*)&sroot[(size_t)b*Hc + c0] = s;
}

__global__ __launch_bounds__(256)
void k_gemm_root(const float* __restrict__ sroot, const float* __restrict__ Wn,
                 const float* __restrict__ Xw, const int* __restrict__ root_wid,
                 float* __restrict__ out)
{
  __shared__ float As[BK][64];
  __shared__ float Bs[BK][64];
  const int tid  = threadIdx.x;
  const int row0 = blockIdx.x*64, col0 = blockIdx.y*64;
  const int ty = tid>>4, tx = tid&15;
  float acc[4][4] = {};
  for (int kt=0; kt<Hc; kt+=BK) {
#pragma unroll
    for (int i=0;i<2;i++){
      const int f  = tid + i*256;
      const int r  = f>>3, kg = f&7;
      const int gr = row0 + r;
      const float4 a4 = *(const float4*)&sroot[(size_t)gr*Hc + kt + kg*4];
      const float av_[4]={a4.x,a4.y,a4.z,a4.w};
#pragma unroll
      for (int j=0;j<4;j++){
        const int k = kg*4+j;
        As[k][r ^ ((k&7)<<2)] = av_[j];
      }
      const int kb = f>>4, cg = f&15;
      *(float4*)&Bs[kb][cg*4] = *(const float4*)&Wn[(size_t)(kt+kb)*Hc + col0 + cg*4];
    }
    __syncthreads();
#pragma unroll
    for (int k=0;k<BK;k++){
      const float4 av = *(const float4*)&As[k][(ty*4) ^ ((k&7)<<2)];
      const float4 bv = *(const float4*)&Bs[k][tx*4];
      const float aa[4]={av.x,av.y,av.z,av.w}, bb[4]={bv.x,bv.y,bv.z,bv.w};
#pragma unroll
      for (int i2=0;i2<4;i2++)
#pragma unroll
        for (int j2=0;j2<4;j2++)
          acc[i2][j2] = fmaf(aa[i2], bb[j2], acc[i2][j2]);
    }
    __syncthreads();
  }
  const int gc0 = col0 + tx*4;
#pragma unroll
  for (int i=0;i<4;i++){
    const int gr  = row0 + ty*4 + i;
    const int wid = root_wid[gr];
    const float4 xw = *(const float4*)&Xw[(size_t)wid*Hc + gc0];
    const float xwv[4]={xw.x,xw.y,xw.z,xw.w};
    float4 o;
    o.x = fmaxf(0.f, acc[i][0]+xwv[0]);
    o.y = fmaxf(0.f, acc[i][1]+xwv[1]);
    o.z = fmaxf(0.f, acc[i][2]+xwv[2]);
    o.w = fmaxf(0.f, acc[i][3]+xwv[3]);
    *(float4*)&out[(size_t)gr*Hc + gc0] = o;
  }
}

// ---------------------------------------------------------------------------
extern "C" void kernel_launch(void* const* d_in, const int* in_sizes, int n_in,
                              void* d_out, int out_size, void* d_ws, size_t ws_size,
                              hipStream_t stream)
{
  const int*   msg_wid  = (const int*)d_in[0];
  const int*   msg_nei  = (const int*)d_in[1];
  const int*   step_ids = (const int*)d_in[2];
  const int*   root_wid = (const int*)d_in[3];
  const int*   root_nei = (const int*)d_in[4];
  const float* emb  = (const float*)d_in[5];
  const float* Wz_w = (const float*)d_in[6];
  const float* Wz_b = (const float*)d_in[7];
  const float* Wr_w = (const float*)d_in[8];
  const float* Ur_w = (const float*)d_in[9];
  const float* Ur_b = (const float*)d_in[10];
  const float* Wh_w = (const float*)d_in[11];
  const float* Wh_b = (const float*)d_in[12];
  const float* W_w  = (const float*)d_in[13];
  const float* W_b  = (const float*)d_in[14];

  float* h    = (float*)d_out;                       // [M][H] -> output 0
  float* rout = (float*)d_out + (size_t)Mc*Hc;       // [B][H] -> output 1

  // workspace layout (floats)
  const size_t need = ((size_t)Mc + 2*(size_t)EMAXc + 4*(size_t)Vc + (size_t)Bc)
                      * (size_t)Hc * sizeof(float);
  if (ws_size < need) return;   // insufficient scratch: bail (will fail check loudly)
  float* ws   = (float*)d_ws;
  float* u    = ws;                           size_t off = (size_t)Mc*Hc;
  float* sumh = ws + off;                     off += (size_t)EMAXc*Hc;
  float* sumg = ws + off;                     off += (size_t)EMAXc*Hc;
  float* Xz   = ws + off;                     off += (size_t)Vc*Hc;
  float* Xr   = ws + off;                     off += (size_t)Vc*Hc;
  float* Xh   = ws + off;                     off += (size_t)Vc*Hc;
  float* Xw   = ws + off;                     off += (size_t)Vc*Hc;
  float* sroot= ws + off;

  const dim3 blk(256);

  // ---- precompute vocab tables (biases folded in; Xr carries Ur_b) ----
  const dim3 gx((Vc+63)/64, Hc/64);
  k_gemm_bias<<<gx, blk, 0, stream>>>(emb, Wz_w,               Wz_b, Xz, Vc);
  k_gemm_bias<<<gx, blk, 0, stream>>>(emb, Wr_w,               Ur_b, Xr, Vc);
  k_gemm_bias<<<gx, blk, 0, stream>>>(emb, Wh_w,               Wh_b, Xh, Vc);
  k_gemm_bias<<<gx, blk, 0, stream>>>(emb, W_w,                W_b,  Xw, Vc);

  const float* Uz = Wz_w + (size_t)Hc*Hc;   // rows H..2H-1
  const float* Uh = Wh_w + (size_t)Hc*Hc;
  const float* Wn = W_w  + (size_t)Hc*Hc;

  // exact per-step message counts (fixed by the K=4, depth-3 tree)
  static const int Esz[Tc] = {32768, 8192, 2048, 2048, 8192, 32768};
  for (int t=0; t<Tc; ++t){
    const int E = Esz[t];
    const int* ids = step_ids + (size_t)t*EMAXc;
    k_gather_step<<<dim3(E/2), blk, 0, stream>>>(ids, msg_nei, msg_wid,
                                                 h, u, Xr, sumh, sumg);
    k_gemm_step<<<dim3(E/64, Hc/64), blk, 0, stream>>>(sumh, sumg, Uz, Uh,
                                                       Xz, Xh, ids, msg_wid, h);
    k_gemm_u<<<dim3(E/64, Hc/64), blk, 0, stream>>>(h, ids, Ur_w, u);
  }

  // ---- root aggregation ----
  k_gather_root<<<dim3(Bc/2), blk, 0, stream>>>(root_nei, h, sroot);
  k_gemm_root<<<dim3(Bc/64, Hc/64), blk, 0, stream>>>(sroot, Wn, Xw, root_wid, rout);
}

// Round 7
// 1747.522 us; speedup vs baseline: 1.3660x; 1.3660x over previous
//
#include <hip/hip_runtime.h>
#include <math.h>

// ---------------------------------------------------------------------------
// TreeEncoder on MI355X — round 7: split-bf16 MFMA GEMMs.
//   z    = sig(Xz[wid] + sum_h @ Uz)
//   r_ij = sig(Xr[wid_i] + u_j),  u = h @ Ur   (precomputed per message)
//   pre  = tanh(Xh[wid] + sum_gated @ Uh)
//   h'   = (1-z)*sum_h + z*pre ;  u' = h' @ Ur
// All E×512×512 GEMMs run on matrix cores with exact hi/lo bf16 splitting
// (3 MFMA passes: hh + hl + lh; missing ll term ~2^-18 relative).
// A and B operands are pre-packed into per-lane fragment layouts so the
// K-loop is pure {global 16B loads + MFMA} — no LDS, no barriers.
// Fragment convention (16x16x32): tile (tr,tk); element (lane,j) holds
//   A[tr*16 + (lane&15)][tk*32 + 8*(lane>>4) + j]   (same mapping for B cols)
// Correct for any consistent HW k-grouping since A/B use the same bijection.
// C/D layout (HW-verified): col = lane&15, row = (lane>>4)*4 + reg.
// Steps chunked at CE=8192 rows -> workspace 255.7 MB (< 322 MB proven OK).
// ---------------------------------------------------------------------------

namespace {
constexpr int Hc    = 512;
constexpr int Vc    = 1000;
constexpr int Bc    = 512;
constexpr int NBc   = 8;
constexpr int Tc    = 6;
constexpr int Mc    = 86016;     // B * 2*(N-1)
constexpr int EMAXc = 32768;
constexpr int CEc   = 8192;      // chunk rows for per-step scratch
constexpr int BKf   = 32;        // f32 helper-GEMM K tile
}

typedef __attribute__((ext_vector_type(8))) short bf16x8;
typedef __attribute__((ext_vector_type(4))) float f32x4;
typedef unsigned short u16;
typedef __attribute__((ext_vector_type(4))) u16 u16x4;
typedef __attribute__((ext_vector_type(8))) u16 u16x8;

__device__ __forceinline__ float sigm_(float x){ return 1.0f/(1.0f+expf(-x)); }
__device__ __forceinline__ u16 f2bf(float x){
  unsigned int v = __float_as_uint(x);
  v += 0x7fffu + ((v>>16)&1u);
  return (u16)(v>>16);
}
__device__ __forceinline__ float bf2f(u16 s){ return __uint_as_float(((unsigned)s)<<16); }

// ---------------- f32 helper GEMM: X = emb @ W + bias (V rows) --------------
__global__ __launch_bounds__(256)
void k_gemm_bias(const float* __restrict__ A, const float* __restrict__ W,
                 const float* __restrict__ bias, float* __restrict__ C, int Mrows)
{
  __shared__ float As[BKf][64];
  __shared__ float Bs[BKf][64];
  const int tid  = threadIdx.x;
  const int row0 = blockIdx.x*64, col0 = blockIdx.y*64;
  const int ty = tid>>4, tx = tid&15;
  float acc[4][4] = {};
  for (int kt=0; kt<Hc; kt+=BKf) {
#pragma unroll
    for (int i=0;i<2;i++){
      const int f  = tid + i*256;
      const int r  = f>>3, kg = f&7;
      const int gr = row0 + r;
      float4 a4 = make_float4(0.f,0.f,0.f,0.f);
      if (gr < Mrows) a4 = *(const float4*)&A[(size_t)gr*Hc + kt + kg*4];
      const float av_[4]={a4.x,a4.y,a4.z,a4.w};
#pragma unroll
      for (int j=0;j<4;j++){
        const int k = kg*4+j;
        As[k][r ^ ((k&7)<<2)] = av_[j];
      }
      const int kb = f>>4, cg = f&15;
      *(float4*)&Bs[kb][cg*4] = *(const float4*)&W[(size_t)(kt+kb)*Hc + col0 + cg*4];
    }
    __syncthreads();
#pragma unroll
    for (int k=0;k<BKf;k++){
      const float4 av = *(const float4*)&As[k][(ty*4) ^ ((k&7)<<2)];
      const float4 bv = *(const float4*)&Bs[k][tx*4];
      const float aa[4]={av.x,av.y,av.z,av.w}, bb[4]={bv.x,bv.y,bv.z,bv.w};
#pragma unroll
      for (int i2=0;i2<4;i2++)
#pragma unroll
        for (int j2=0;j2<4;j2++)
          acc[i2][j2] = fmaf(aa[i2], bb[j2], acc[i2][j2]);
    }
    __syncthreads();
  }
  const int gc0 = col0 + tx*4;
  const float4 bv = *(const float4*)&bias[gc0];
  const float bb[4]={bv.x,bv.y,bv.z,bv.w};
#pragma unroll
  for (int i=0;i<4;i++){
    const int gr = row0 + ty*4 + i;
    if (gr >= Mrows) break;
    float4 o = make_float4(acc[i][0]+bb[0], acc[i][1]+bb[1],
                           acc[i][2]+bb[2], acc[i][3]+bb[3]);
    *(float4*)&C[(size_t)gr*Hc + gc0] = o;
  }
}

// ---------------- pack one 512x512 weight (row=k) into hi/lo fragments ------
__global__ __launch_bounds__(256)
void k_pack_w(const float* __restrict__ W, u16* __restrict__ hi, u16* __restrict__ lo)
{
  const int q = blockIdx.x*256 + threadIdx.x;   // 32768 = 32 tn * 16 tk * 64 lanes
  const int lane = q & 63, tk = (q>>6)&15, tn = q>>10;
  u16x8 h8, l8;
#pragma unroll
  for (int j=0;j<8;j++){
    const int k = tk*32 + (lane>>4)*8 + j;
    const int n = tn*16 + (lane&15);
    const float v = W[(size_t)k*Hc + n];
    const u16 h = f2bf(v);
    h8[j] = h; l8[j] = f2bf(v - bf2f(h));
  }
  const size_t off = ((size_t)(tn*16+tk)*64 + lane)*8;
  *(u16x8*)&hi[off] = h8;
  *(u16x8*)&lo[off] = l8;
}

// ---------------- per-step gather: sum_h (f32 + packed), sum_gated (packed) -
__global__ __launch_bounds__(256)
void k_gather_step(const int* __restrict__ ids, const int* __restrict__ msg_nei,
                   const int* __restrict__ msg_wid, const float* __restrict__ h,
                   const float* __restrict__ u, const float* __restrict__ Xr,
                   float* __restrict__ sumh,
                   u16* __restrict__ AhH, u16* __restrict__ AhL,
                   u16* __restrict__ AgH, u16* __restrict__ AgL)
{
  const int e  = blockIdx.x*2 + (threadIdx.x>>7);   // chunk-local row
  const int c0 = (threadIdx.x&127)<<2;
  const int idx = ids[e];
  float sh[4] = {0.f,0.f,0.f,0.f};
  float sg[4] = {0.f,0.f,0.f,0.f};
  if (idx < Mc) {
    const int wid = msg_wid[idx];
    const float4 xr = *(const float4*)&Xr[(size_t)wid*Hc + c0];
    const float xrv[4]={xr.x,xr.y,xr.z,xr.w};
#pragma unroll
    for (int kk=0; kk<NBc; kk++){
      const int j = msg_nei[(size_t)idx*NBc + kk];
      if (j >= Mc) break;            // PAD tail
      const float4 hv = *(const float4*)&h[(size_t)j*Hc + c0];
      const float4 uv = *(const float4*)&u[(size_t)j*Hc + c0];
      const float hvv[4]={hv.x,hv.y,hv.z,hv.w}, uvv[4]={uv.x,uv.y,uv.z,uv.w};
#pragma unroll
      for (int q=0;q<4;q++){
        sh[q] += hvv[q];
        sg[q] += sigm_(xrv[q]+uvv[q])*hvv[q];
      }
    }
  }
  *(float4*)&sumh[(size_t)e*Hc + c0] = make_float4(sh[0],sh[1],sh[2],sh[3]);
  // pack both A operands (hi/lo) into fragment layout
  const int te = e>>4, tk = c0>>5, lane = (e&15) + ((c0>>3)&3)*16, j0 = c0&7;
  const size_t pb = ((size_t)(te*16+tk)*64 + lane)*8 + j0;
  u16x4 hh, hl, gh, gl;
#pragma unroll
  for (int q=0;q<4;q++){
    const u16 a = f2bf(sh[q]); hh[q]=a; hl[q]=f2bf(sh[q]-bf2f(a));
    const u16 b = f2bf(sg[q]); gh[q]=b; gl[q]=f2bf(sg[q]-bf2f(b));
  }
  *(u16x4*)&AhH[pb]=hh; *(u16x4*)&AhL[pb]=hl;
  *(u16x4*)&AgH[pb]=gh; *(u16x4*)&AgL[pb]=gl;
}

// ---------------- dual split-bf16 MFMA GEMM + GRU epilogue + Hp repack ------
// grid (CE/64, 4); block 256 = 4 waves; wave tile 64 rows x 32 cols.
__global__ __launch_bounds__(256)
void k_gemm_step_mfma(const u16* __restrict__ AhH, const u16* __restrict__ AhL,
                      const u16* __restrict__ AgH, const u16* __restrict__ AgL,
                      const float* __restrict__ sumh,
                      const u16* __restrict__ BzH, const u16* __restrict__ BzL,
                      const u16* __restrict__ BhH, const u16* __restrict__ BhL,
                      const float* __restrict__ Xz, const float* __restrict__ Xh,
                      const int* __restrict__ ids, const int* __restrict__ msg_wid,
                      float* __restrict__ hout,
                      u16* __restrict__ HpH, u16* __restrict__ HpL)
{
  __shared__ float lt[64][132];          // new_h block tile (padded rows)
  __shared__ int s_idx[64];
  __shared__ int s_wid[64];
  const int tid  = threadIdx.x;
  const int w    = tid>>6, lane = tid&63;
  const int row0 = blockIdx.x*64;        // chunk-local
  const int col0 = blockIdx.y*128;
  if (tid < 64){
    const int ix = ids[row0 + tid];
    s_idx[tid] = ix;
    s_wid[tid] = (ix < Mc) ? msg_wid[ix] : 0;
  }
  f32x4 accz[4][2] = {};
  f32x4 acch[4][2] = {};
  const int cbase = col0 + w*32;
  const int tn0   = cbase>>4;            // global n-tile of nt=0
  const int te0   = row0>>4;
  for (int kt=0; kt<16; ++kt){
    bf16x8 bzh[2], bzl[2], bhh[2], bhl[2];
#pragma unroll
    for (int nt=0; nt<2; ++nt){
      const size_t bo = ((size_t)((tn0+nt)*16 + kt)*64 + lane)*8;
      bzh[nt] = *(const bf16x8*)&BzH[bo];
      bzl[nt] = *(const bf16x8*)&BzL[bo];
      bhh[nt] = *(const bf16x8*)&BhH[bo];
      bhl[nt] = *(const bf16x8*)&BhL[bo];
    }
#pragma unroll
    for (int mt=0; mt<4; ++mt){
      const size_t ao = ((size_t)((te0+mt)*16 + kt)*64 + lane)*8;
      const bf16x8 ahh = *(const bf16x8*)&AhH[ao];
      const bf16x8 ahl = *(const bf16x8*)&AhL[ao];
      const bf16x8 agh = *(const bf16x8*)&AgH[ao];
      const bf16x8 agl = *(const bf16x8*)&AgL[ao];
#pragma unroll
      for (int nt=0; nt<2; ++nt){
        accz[mt][nt] = __builtin_amdgcn_mfma_f32_16x16x32_bf16(ahh, bzh[nt], accz[mt][nt], 0,0,0);
        accz[mt][nt] = __builtin_amdgcn_mfma_f32_16x16x32_bf16(ahh, bzl[nt], accz[mt][nt], 0,0,0);
        accz[mt][nt] = __builtin_amdgcn_mfma_f32_16x16x32_bf16(ahl, bzh[nt], accz[mt][nt], 0,0,0);
        acch[mt][nt] = __builtin_amdgcn_mfma_f32_16x16x32_bf16(agh, bhh[nt], acch[mt][nt], 0,0,0);
        acch[mt][nt] = __builtin_amdgcn_mfma_f32_16x16x32_bf16(agh, bhl[nt], acch[mt][nt], 0,0,0);
        acch[mt][nt] = __builtin_amdgcn_mfma_f32_16x16x32_bf16(agl, bhh[nt], acch[mt][nt], 0,0,0);
      }
    }
  }
  __syncthreads();                       // s_idx/s_wid visible
  // GRU epilogue: scatter h' to d_out + stage into LDS for repack
#pragma unroll
  for (int mt=0; mt<4; ++mt){
#pragma unroll
    for (int nt=0; nt<2; ++nt){
#pragma unroll
      for (int r=0; r<4; ++r){
        const int rl = mt*16 + (lane>>4)*4 + r;
        const int c  = cbase + nt*16 + (lane&15);
        const int wid = s_wid[rl];
        const float z = sigm_(Xz[(size_t)wid*Hc + c] + accz[mt][nt][r]);
        const float p = tanhf(Xh[(size_t)wid*Hc + c] + acch[mt][nt][r]);
        const float shv = sumh[(size_t)(row0+rl)*Hc + c];
        const float nh = (1.0f - z)*shv + z*p;
        const int idx = s_idx[rl];
        if (idx < Mc) hout[(size_t)idx*Hc + c] = nh;
        lt[rl][c - col0] = nh;
      }
    }
  }
  __syncthreads();
  // repack new_h into hi/lo A-fragments for the u-GEMM (1024 16B chunks)
#pragma unroll
  for (int i=0;i<4;i++){
    const int q   = tid + i*256;
    const int tel = q>>8, tkl = (q>>6)&3, ln = q&63;
    const int row = tel*16 + (ln&15);
    const int cl0 = tkl*32 + (ln>>4)*8;
    u16x8 h8, l8;
#pragma unroll
    for (int j=0;j<8;j++){
      const float v = lt[row][cl0+j];
      const u16 a = f2bf(v);
      h8[j] = a; l8[j] = f2bf(v - bf2f(a));
    }
    const size_t off = ((size_t)((te0+tel)*16 + (col0>>5) + tkl)*64 + ln)*8;
    *(u16x8*)&HpH[off] = h8;
    *(u16x8*)&HpL[off] = l8;
  }
}

// ---------------- u = h' @ Ur (split-bf16 MFMA, scatter epilogue) -----------
__global__ __launch_bounds__(256)
void k_gemm_u_mfma(const u16* __restrict__ HpH, const u16* __restrict__ HpL,
                   const u16* __restrict__ BrH, const u16* __restrict__ BrL,
                   const int* __restrict__ ids, float* __restrict__ u)
{
  __shared__ int s_idx[64];
  const int tid  = threadIdx.x;
  const int w    = tid>>6, lane = tid&63;
  const int row0 = blockIdx.x*64;
  const int col0 = blockIdx.y*128;
  if (tid < 64) s_idx[tid] = ids[row0 + tid];
  __syncthreads();
  f32x4 acc[4][2] = {};
  const int cbase = col0 + w*32;
  const int tn0   = cbase>>4;
  const int te0   = row0>>4;
  for (int kt=0; kt<16; ++kt){
    bf16x8 bh[2], bl[2];
#pragma unroll
    for (int nt=0; nt<2; ++nt){
      const size_t bo = ((size_t)((tn0+nt)*16 + kt)*64 + lane)*8;
      bh[nt] = *(const bf16x8*)&BrH[bo];
      bl[nt] = *(const bf16x8*)&BrL[bo];
    }
#pragma unroll
    for (int mt=0; mt<4; ++mt){
      const size_t ao = ((size_t)((te0+mt)*16 + kt)*64 + lane)*8;
      const bf16x8 ah = *(const bf16x8*)&HpH[ao];
      const bf16x8 al = *(const bf16x8*)&HpL[ao];
#pragma unroll
      for (int nt=0; nt<2; ++nt){
        acc[mt][nt] = __builtin_amdgcn_mfma_f32_16x16x32_bf16(ah, bh[nt], acc[mt][nt], 0,0,0);
        acc[mt][nt] = __builtin_amdgcn_mfma_f32_16x16x32_bf16(ah, bl[nt], acc[mt][nt], 0,0,0);
        acc[mt][nt] = __builtin_amdgcn_mfma_f32_16x16x32_bf16(al, bh[nt], acc[mt][nt], 0,0,0);
      }
    }
  }
#pragma unroll
  for (int mt=0; mt<4; ++mt){
#pragma unroll
    for (int nt=0; nt<2; ++nt){
#pragma unroll
      for (int r=0; r<4; ++r){
        const int rl = mt*16 + (lane>>4)*4 + r;
        const int c  = cbase + nt*16 + (lane&15);
        const int idx = s_idx[rl];
        if (idx < Mc) u[(size_t)idx*Hc + c] = acc[mt][nt][r];
      }
    }
  }
}

// ---------------- root gather + root GEMM (f32, tiny) -----------------------
__global__ __launch_bounds__(256)
void k_gather_root(const int* __restrict__ root_nei, const float* __restrict__ h,
                   float* __restrict__ sroot)
{
  const int b  = blockIdx.x*2 + (threadIdx.x>>7);
  const int c0 = (threadIdx.x&127)<<2;
  float4 s = make_float4(0.f,0.f,0.f,0.f);
#pragma unroll
  for (int kk=0; kk<NBc; kk++){
    const int j = root_nei[(size_t)b*NBc + kk];
    if (j >= Mc) break;
    const float4 hv = *(const float4*)&h[(size_t)j*Hc + c0];
    s.x+=hv.x; s.y+=hv.y; s.z+=hv.z; s.w+=hv.w;
  }
  *(float4*)&sroot[(size_t)b*Hc + c0] = s;
}

__global__ __launch_bounds__(256)
void k_gemm_root(const float* __restrict__ sroot, const float* __restrict__ Wn,
                 const float* __restrict__ Xw, const int* __restrict__ root_wid,
                 float* __restrict__ out)
{
  __shared__ float As[BKf][64];
  __shared__ float Bs[BKf][64];
  const int tid  = threadIdx.x;
  const int row0 = blockIdx.x*64, col0 = blockIdx.y*64;
  const int ty = tid>>4, tx = tid&15;
  float acc[4][4] = {};
  for (int kt=0; kt<Hc; kt+=BKf) {
#pragma unroll
    for (int i=0;i<2;i++){
      const int f  = tid + i*256;
      const int r  = f>>3, kg = f&7;
      const int gr = row0 + r;
      const float4 a4 = *(const float4*)&sroot[(size_t)gr*Hc + kt + kg*4];
      const float av_[4]={a4.x,a4.y,a4.z,a4.w};
#pragma unroll
      for (int j=0;j<4;j++){
        const int k = kg*4+j;
        As[k][r ^ ((k&7)<<2)] = av_[j];
      }
      const int kb = f>>4, cg = f&15;
      *(float4*)&Bs[kb][cg*4] = *(const float4*)&Wn[(size_t)(kt+kb)*Hc + col0 + cg*4];
    }
    __syncthreads();
#pragma unroll
    for (int k=0;k<BKf;k++){
      const float4 av = *(const float4*)&As[k][(ty*4) ^ ((k&7)<<2)];
      const float4 bv = *(const float4*)&Bs[k][tx*4];
      const float aa[4]={av.x,av.y,av.z,av.w}, bb[4]={bv.x,bv.y,bv.z,bv.w};
#pragma unroll
      for (int i2=0;i2<4;i2++)
#pragma unroll
        for (int j2=0;j2<4;j2++)
          acc[i2][j2] = fmaf(aa[i2], bb[j2], acc[i2][j2]);
    }
    __syncthreads();
  }
  const int gc0 = col0 + tx*4;
#pragma unroll
  for (int i=0;i<4;i++){
    const int gr  = row0 + ty*4 + i;
    const int wid = root_wid[gr];
    const float4 xw = *(const float4*)&Xw[(size_t)wid*Hc + gc0];
    float4 o;
    o.x = fmaxf(0.f, acc[i][0]+xw.x);
    o.y = fmaxf(0.f, acc[i][1]+xw.y);
    o.z = fmaxf(0.f, acc[i][2]+xw.z);
    o.w = fmaxf(0.f, acc[i][3]+xw.w);
    *(float4*)&out[(size_t)gr*Hc + gc0] = o;
  }
}

// ---------------------------------------------------------------------------
extern "C" void kernel_launch(void* const* d_in, const int* in_sizes, int n_in,
                              void* d_out, int out_size, void* d_ws, size_t ws_size,
                              hipStream_t stream)
{
  const int*   msg_wid  = (const int*)d_in[0];
  const int*   msg_nei  = (const int*)d_in[1];
  const int*   step_ids = (const int*)d_in[2];
  const int*   root_wid = (const int*)d_in[3];
  const int*   root_nei = (const int*)d_in[4];
  const float* emb  = (const float*)d_in[5];
  const float* Wz_w = (const float*)d_in[6];
  const float* Wz_b = (const float*)d_in[7];
  const float* Wr_w = (const float*)d_in[8];
  const float* Ur_w = (const float*)d_in[9];
  const float* Ur_b = (const float*)d_in[10];
  const float* Wh_w = (const float*)d_in[11];
  const float* Wh_b = (const float*)d_in[12];
  const float* W_w  = (const float*)d_in[13];
  const float* W_b  = (const float*)d_in[14];

  float* h    = (float*)d_out;                       // [M][H]
  float* rout = (float*)d_out + (size_t)Mc*Hc;       // [B][H]

  // ---- workspace layout (bytes; every piece is 256B-aligned by size) ----
  constexpr size_t SZ_U    = (size_t)Mc*Hc*4;        // 176,160,768
  constexpr size_t SZ_SUMH = (size_t)CEc*Hc*4;       //  16,777,216
  constexpr size_t SZ_PK   = (size_t)CEc*Hc*2;       //   8,388,608 (x6)
  constexpr size_t SZ_X    = (size_t)Vc*Hc*4;        //   2,048,000 (x4)
  constexpr size_t SZ_BP   = (size_t)Hc*Hc*2;        //     524,288 (x6)
  constexpr size_t SZ_ROOT = (size_t)Bc*Hc*4;        //   1,048,576
  constexpr size_t NEED = SZ_U + SZ_SUMH + 6*SZ_PK + 4*SZ_X + 6*SZ_BP + SZ_ROOT;
  if (ws_size < NEED) return;   // 255.7 MB; round-6 proved >=322 MB available

  char* p = (char*)d_ws;
  float* u    = (float*)p;  p += SZ_U;
  float* sumh = (float*)p;  p += SZ_SUMH;
  u16* AhH = (u16*)p; p += SZ_PK;
  u16* AhL = (u16*)p; p += SZ_PK;
  u16* AgH = (u16*)p; p += SZ_PK;
  u16* AgL = (u16*)p; p += SZ_PK;
  u16* HpH = (u16*)p; p += SZ_PK;
  u16* HpL = (u16*)p; p += SZ_PK;
  float* Xz = (float*)p; p += SZ_X;
  float* Xr = (float*)p; p += SZ_X;
  float* Xh = (float*)p; p += SZ_X;
  float* Xw = (float*)p; p += SZ_X;
  u16* BzH = (u16*)p; p += SZ_BP;
  u16* BzL = (u16*)p; p += SZ_BP;
  u16* BhH = (u16*)p; p += SZ_BP;
  u16* BhL = (u16*)p; p += SZ_BP;
  u16* BrH = (u16*)p; p += SZ_BP;
  u16* BrL = (u16*)p; p += SZ_BP;
  float* sroot = (float*)p;

  const dim3 blk(256);

  // ---- vocab tables (f32; biases folded; Xr carries Ur_b) ----
  const dim3 gx((Vc+63)/64, Hc/64);
  k_gemm_bias<<<gx, blk, 0, stream>>>(emb, Wz_w, Wz_b, Xz, Vc);
  k_gemm_bias<<<gx, blk, 0, stream>>>(emb, Wr_w, Ur_b, Xr, Vc);
  k_gemm_bias<<<gx, blk, 0, stream>>>(emb, Wh_w, Wh_b, Xh, Vc);
  k_gemm_bias<<<gx, blk, 0, stream>>>(emb, W_w,  W_b,  Xw, Vc);

  // ---- pack recurrent weights into hi/lo MFMA fragments ----
  const float* Uz = Wz_w + (size_t)Hc*Hc;
  const float* Uh = Wh_w + (size_t)Hc*Hc;
  const float* Wn = W_w  + (size_t)Hc*Hc;
  k_pack_w<<<128, blk, 0, stream>>>(Uz,   BzH, BzL);
  k_pack_w<<<128, blk, 0, stream>>>(Uh,   BhH, BhL);
  k_pack_w<<<128, blk, 0, stream>>>(Ur_w, BrH, BrL);

  // ---- message-passing steps (chunked at CE=8192 rows) ----
  static const int Esz[Tc] = {32768, 8192, 2048, 2048, 8192, 32768};
  for (int t=0; t<Tc; ++t){
    const int E = Esz[t];
    for (int off=0; off<E; off+=CEc){
      const int CE = (E - off < CEc) ? (E - off) : CEc;
      const int* ids = step_ids + (size_t)t*EMAXc + off;
      k_gather_step<<<dim3(CE/2), blk, 0, stream>>>(ids, msg_nei, msg_wid,
                                                    h, u, Xr, sumh,
                                                    AhH, AhL, AgH, AgL);
      k_gemm_step_mfma<<<dim3(CE/64, 4), blk, 0, stream>>>(AhH, AhL, AgH, AgL,
                                                           sumh, BzH, BzL, BhH, BhL,
                                                           Xz, Xh, ids, msg_wid,
                                                           h, HpH, HpL);
      k_gemm_u_mfma<<<dim3(CE/64, 4), blk, 0, stream>>>(HpH, HpL, BrH, BrL, ids, u);
    }
  }

  // ---- root aggregation (tiny) ----
  k_gather_root<<<dim3(Bc/2), blk, 0, stream>>>(root_nei, h, sroot);
  k_gemm_root<<<dim3(Bc/64, Hc/64), blk, 0, stream>>>(sroot, Wn, Xw, root_wid, rout);
}

// Round 9
// 1278.030 us; speedup vs baseline: 1.8678x; 1.3674x over previous
//
#include <hip/hip_runtime.h>
#include <math.h>

// ---------------------------------------------------------------------------
// TreeEncoder on MI355X — round 8: tree-structure algebraic cuts.
//   step 0 (leaf->parent, 38% of rows): sum_h==sum_gated==0 exactly
//     -> h' = sig(Xz[wid]) * tanh(Xh[wid]) = h0[wid]   (vocab-indexed!)
//     -> u' = h0 @ Ur = u0[wid]            (1000-row f32 GEMM)
//     -> step 0 becomes a broadcast scatter of h0/u0.
//   step 5 (parent->leaf, last step): u never consumed -> skip u-GEMM+repack.
// Remaining steps use round-7's split-bf16 MFMA pipeline (3 passes hh+hl+lh).
// Fragment convention (16x16x32): element (lane,j) of tile (tr,tk) holds
//   A[tr*16 + (lane&15)][tk*32 + 8*(lane>>4) + j]  (same bijection for B).
// C/D: col = lane&15, row = (lane>>4)*4 + reg  (HW-verified m89).
// CE=16384 chunk rows; workspace 326.9 MB (fills evidence ws ~531 MB).
// ---------------------------------------------------------------------------

namespace {
constexpr int Hc    = 512;
constexpr int Vc    = 1000;
constexpr int Bc    = 512;
constexpr int NBc   = 8;
constexpr int Tc    = 6;
constexpr int Mc    = 86016;     // B * 2*(N-1)
constexpr int EMAXc = 32768;
constexpr int CEc   = 16384;     // chunk rows for per-step scratch
constexpr int BKf   = 32;        // f32 helper-GEMM K tile
}

typedef __attribute__((ext_vector_type(8))) short bf16x8;
typedef __attribute__((ext_vector_type(4))) float f32x4;
typedef unsigned short u16;
typedef __attribute__((ext_vector_type(4))) u16 u16x4;
typedef __attribute__((ext_vector_type(8))) u16 u16x8;

__device__ __forceinline__ float sigm_(float x){ return 1.0f/(1.0f+expf(-x)); }
__device__ __forceinline__ u16 f2bf(float x){
  unsigned int v = __float_as_uint(x);
  v += 0x7fffu + ((v>>16)&1u);
  return (u16)(v>>16);
}
__device__ __forceinline__ float bf2f(u16 s){ return __uint_as_float(((unsigned)s)<<16); }

// ---------------- f32 helper GEMM: X = emb @ W + bias -----------------------
__global__ __launch_bounds__(256)
void k_gemm_bias(const float* __restrict__ A, const float* __restrict__ W,
                 const float* __restrict__ bias, float* __restrict__ C, int Mrows)
{
  __shared__ float As[BKf][64];
  __shared__ float Bs[BKf][64];
  const int tid  = threadIdx.x;
  const int row0 = blockIdx.x*64, col0 = blockIdx.y*64;
  const int ty = tid>>4, tx = tid&15;
  float acc[4][4] = {};
  for (int kt=0; kt<Hc; kt+=BKf) {
#pragma unroll
    for (int i=0;i<2;i++){
      const int f  = tid + i*256;
      const int r  = f>>3, kg = f&7;
      const int gr = row0 + r;
      float4 a4 = make_float4(0.f,0.f,0.f,0.f);
      if (gr < Mrows) a4 = *(const float4*)&A[(size_t)gr*Hc + kt + kg*4];
      const float av_[4]={a4.x,a4.y,a4.z,a4.w};
#pragma unroll
      for (int j=0;j<4;j++){
        const int k = kg*4+j;
        As[k][r ^ ((k&7)<<2)] = av_[j];
      }
      const int kb = f>>4, cg = f&15;
      *(float4*)&Bs[kb][cg*4] = *(const float4*)&W[(size_t)(kt+kb)*Hc + col0 + cg*4];
    }
    __syncthreads();
#pragma unroll
    for (int k=0;k<BKf;k++){
      const float4 av = *(const float4*)&As[k][(ty*4) ^ ((k&7)<<2)];
      const float4 bv = *(const float4*)&Bs[k][tx*4];
      const float aa[4]={av.x,av.y,av.z,av.w}, bb[4]={bv.x,bv.y,bv.z,bv.w};
#pragma unroll
      for (int i2=0;i2<4;i2++)
#pragma unroll
        for (int j2=0;j2<4;j2++)
          acc[i2][j2] = fmaf(aa[i2], bb[j2], acc[i2][j2]);
    }
    __syncthreads();
  }
  const int gc0 = col0 + tx*4;
  const float4 bv = *(const float4*)&bias[gc0];
  const float bb[4]={bv.x,bv.y,bv.z,bv.w};
#pragma unroll
  for (int i=0;i<4;i++){
    const int gr = row0 + ty*4 + i;
    if (gr >= Mrows) break;
    float4 o = make_float4(acc[i][0]+bb[0], acc[i][1]+bb[1],
                           acc[i][2]+bb[2], acc[i][3]+bb[3]);
    *(float4*)&C[(size_t)gr*Hc + gc0] = o;
  }
}

// ---------------- f32 helper GEMM, no bias (u0 = h0 @ Ur) -------------------
__global__ __launch_bounds__(256)
void k_gemm_plain(const float* __restrict__ A, const float* __restrict__ W,
                  float* __restrict__ C, int Mrows)
{
  __shared__ float As[BKf][64];
  __shared__ float Bs[BKf][64];
  const int tid  = threadIdx.x;
  const int row0 = blockIdx.x*64, col0 = blockIdx.y*64;
  const int ty = tid>>4, tx = tid&15;
  float acc[4][4] = {};
  for (int kt=0; kt<Hc; kt+=BKf) {
#pragma unroll
    for (int i=0;i<2;i++){
      const int f  = tid + i*256;
      const int r  = f>>3, kg = f&7;
      const int gr = row0 + r;
      float4 a4 = make_float4(0.f,0.f,0.f,0.f);
      if (gr < Mrows) a4 = *(const float4*)&A[(size_t)gr*Hc + kt + kg*4];
      const float av_[4]={a4.x,a4.y,a4.z,a4.w};
#pragma unroll
      for (int j=0;j<4;j++){
        const int k = kg*4+j;
        As[k][r ^ ((k&7)<<2)] = av_[j];
      }
      const int kb = f>>4, cg = f&15;
      *(float4*)&Bs[kb][cg*4] = *(const float4*)&W[(size_t)(kt+kb)*Hc + col0 + cg*4];
    }
    __syncthreads();
#pragma unroll
    for (int k=0;k<BKf;k++){
      const float4 av = *(const float4*)&As[k][(ty*4) ^ ((k&7)<<2)];
      const float4 bv = *(const float4*)&Bs[k][tx*4];
      const float aa[4]={av.x,av.y,av.z,av.w}, bb[4]={bv.x,bv.y,bv.z,bv.w};
#pragma unroll
      for (int i2=0;i2<4;i2++)
#pragma unroll
        for (int j2=0;j2<4;j2++)
          acc[i2][j2] = fmaf(aa[i2], bb[j2], acc[i2][j2]);
    }
    __syncthreads();
  }
  const int gc0 = col0 + tx*4;
#pragma unroll
  for (int i=0;i<4;i++){
    const int gr = row0 + ty*4 + i;
    if (gr >= Mrows) break;
    float4 o = make_float4(acc[i][0],acc[i][1],acc[i][2],acc[i][3]);
    *(float4*)&C[(size_t)gr*Hc + gc0] = o;
  }
}

// ---------------- h0[v] = sig(Xz[v]) * tanh(Xh[v])  (vocab table) -----------
__global__ __launch_bounds__(256)
void k_h0(const float* __restrict__ Xz, const float* __restrict__ Xh,
          float* __restrict__ h0)
{
  const int i = blockIdx.x*256 + threadIdx.x;          // over V*H/4
  if (i >= Vc*Hc/4) return;
  const float4 a = ((const float4*)Xz)[i];
  const float4 b = ((const float4*)Xh)[i];
  float4 o;
  o.x = sigm_(a.x)*tanhf(b.x);
  o.y = sigm_(a.y)*tanhf(b.y);
  o.z = sigm_(a.z)*tanhf(b.z);
  o.w = sigm_(a.w)*tanhf(b.w);
  ((float4*)h0)[i] = o;
}

// ---------------- step 0: broadcast h0/u0 to message rows -------------------
__global__ __launch_bounds__(256)
void k_bcast0(const int* __restrict__ ids, const int* __restrict__ msg_wid,
              const float* __restrict__ h0, const float* __restrict__ u0,
              float* __restrict__ h, float* __restrict__ u)
{
  const int e  = blockIdx.x*2 + (threadIdx.x>>7);
  const int c0 = (threadIdx.x&127)<<2;
  const int idx = ids[e];
  const int wid = msg_wid[idx];
  *(float4*)&h[(size_t)idx*Hc + c0] = *(const float4*)&h0[(size_t)wid*Hc + c0];
  *(float4*)&u[(size_t)idx*Hc + c0] = *(const float4*)&u0[(size_t)wid*Hc + c0];
}

// ---------------- pack one 512x512 weight (row=k) into hi/lo fragments ------
__global__ __launch_bounds__(256)
void k_pack_w(const float* __restrict__ W, u16* __restrict__ hi, u16* __restrict__ lo)
{
  const int q = blockIdx.x*256 + threadIdx.x;   // 32768 = 32 tn * 16 tk * 64 lanes
  const int lane = q & 63, tk = (q>>6)&15, tn = q>>10;
  u16x8 h8, l8;
#pragma unroll
  for (int j=0;j<8;j++){
    const int k = tk*32 + (lane>>4)*8 + j;
    const int n = tn*16 + (lane&15);
    const float v = W[(size_t)k*Hc + n];
    const u16 h = f2bf(v);
    h8[j] = h; l8[j] = f2bf(v - bf2f(h));
  }
  const size_t off = ((size_t)(tn*16+tk)*64 + lane)*8;
  *(u16x8*)&hi[off] = h8;
  *(u16x8*)&lo[off] = l8;
}

// ---------------- per-step gather: sum_h (f32 + packed), sum_gated (packed) -
__global__ __launch_bounds__(256)
void k_gather_step(const int* __restrict__ ids, const int* __restrict__ msg_nei,
                   const int* __restrict__ msg_wid, const float* __restrict__ h,
                   const float* __restrict__ u, const float* __restrict__ Xr,
                   float* __restrict__ sumh,
                   u16* __restrict__ AhH, u16* __restrict__ AhL,
                   u16* __restrict__ AgH, u16* __restrict__ AgL)
{
  const int e  = blockIdx.x*2 + (threadIdx.x>>7);   // chunk-local row
  const int c0 = (threadIdx.x&127)<<2;
  const int idx = ids[e];
  float sh[4] = {0.f,0.f,0.f,0.f};
  float sg[4] = {0.f,0.f,0.f,0.f};
  if (idx < Mc) {
    const int wid = msg_wid[idx];
    const float4 xr = *(const float4*)&Xr[(size_t)wid*Hc + c0];
    const float xrv[4]={xr.x,xr.y,xr.z,xr.w};
#pragma unroll
    for (int kk=0; kk<NBc; kk++){
      const int j = msg_nei[(size_t)idx*NBc + kk];
      if (j >= Mc) break;            // PAD tail
      const float4 hv = *(const float4*)&h[(size_t)j*Hc + c0];
      const float4 uv = *(const float4*)&u[(size_t)j*Hc + c0];
      const float hvv[4]={hv.x,hv.y,hv.z,hv.w}, uvv[4]={uv.x,uv.y,uv.z,uv.w};
#pragma unroll
      for (int q=0;q<4;q++){
        sh[q] += hvv[q];
        sg[q] += sigm_(xrv[q]+uvv[q])*hvv[q];
      }
    }
  }
  *(float4*)&sumh[(size_t)e*Hc + c0] = make_float4(sh[0],sh[1],sh[2],sh[3]);
  const int te = e>>4, tk = c0>>5, lane = (e&15) + ((c0>>3)&3)*16, j0 = c0&7;
  const size_t pb = ((size_t)(te*16+tk)*64 + lane)*8 + j0;
  u16x4 hh, hl, gh, gl;
#pragma unroll
  for (int q=0;q<4;q++){
    const u16 a = f2bf(sh[q]); hh[q]=a; hl[q]=f2bf(sh[q]-bf2f(a));
    const u16 b = f2bf(sg[q]); gh[q]=b; gl[q]=f2bf(sg[q]-bf2f(b));
  }
  *(u16x4*)&AhH[pb]=hh; *(u16x4*)&AhL[pb]=hl;
  *(u16x4*)&AgH[pb]=gh; *(u16x4*)&AgL[pb]=gl;
}

// ---------------- dual split-bf16 MFMA GEMM + GRU epilogue (+opt repack) ----
// grid (CE/64, 4); block 256 = 4 waves; wave tile 64 rows x 32 cols.
__global__ __launch_bounds__(256)
void k_gemm_step_mfma(const u16* __restrict__ AhH, const u16* __restrict__ AhL,
                      const u16* __restrict__ AgH, const u16* __restrict__ AgL,
                      const float* __restrict__ sumh,
                      const u16* __restrict__ BzH, const u16* __restrict__ BzL,
                      const u16* __restrict__ BhH, const u16* __restrict__ BhL,
                      const float* __restrict__ Xz, const float* __restrict__ Xh,
                      const int* __restrict__ ids, const int* __restrict__ msg_wid,
                      float* __restrict__ hout,
                      u16* __restrict__ HpH, u16* __restrict__ HpL,
                      const int do_repack)
{
  __shared__ float lt[64][132];
  __shared__ int s_idx[64];
  __shared__ int s_wid[64];
  const int tid  = threadIdx.x;
  const int w    = tid>>6, lane = tid&63;
  const int row0 = blockIdx.x*64;        // chunk-local
  const int col0 = blockIdx.y*128;
  if (tid < 64){
    const int ix = ids[row0 + tid];
    s_idx[tid] = ix;
    s_wid[tid] = (ix < Mc) ? msg_wid[ix] : 0;
  }
  f32x4 accz[4][2] = {};
  f32x4 acch[4][2] = {};
  const int cbase = col0 + w*32;
  const int tn0   = cbase>>4;
  const int te0   = row0>>4;
  for (int kt=0; kt<16; ++kt){
    bf16x8 bzh[2], bzl[2], bhh[2], bhl[2];
#pragma unroll
    for (int nt=0; nt<2; ++nt){
      const size_t bo = ((size_t)((tn0+nt)*16 + kt)*64 + lane)*8;
      bzh[nt] = *(const bf16x8*)&BzH[bo];
      bzl[nt] = *(const bf16x8*)&BzL[bo];
      bhh[nt] = *(const bf16x8*)&BhH[bo];
      bhl[nt] = *(const bf16x8*)&BhL[bo];
    }
#pragma unroll
    for (int mt=0; mt<4; ++mt){
      const size_t ao = ((size_t)((te0+mt)*16 + kt)*64 + lane)*8;
      const bf16x8 ahh = *(const bf16x8*)&AhH[ao];
      const bf16x8 ahl = *(const bf16x8*)&AhL[ao];
      const bf16x8 agh = *(const bf16x8*)&AgH[ao];
      const bf16x8 agl = *(const bf16x8*)&AgL[ao];
#pragma unroll
      for (int nt=0; nt<2; ++nt){
        accz[mt][nt] = __builtin_amdgcn_mfma_f32_16x16x32_bf16(ahh, bzh[nt], accz[mt][nt], 0,0,0);
        accz[mt][nt] = __builtin_amdgcn_mfma_f32_16x16x32_bf16(ahh, bzl[nt], accz[mt][nt], 0,0,0);
        accz[mt][nt] = __builtin_amdgcn_mfma_f32_16x16x32_bf16(ahl, bzh[nt], accz[mt][nt], 0,0,0);
        acch[mt][nt] = __builtin_amdgcn_mfma_f32_16x16x32_bf16(agh, bhh[nt], acch[mt][nt], 0,0,0);
        acch[mt][nt] = __builtin_amdgcn_mfma_f32_16x16x32_bf16(agh, bhl[nt], acch[mt][nt], 0,0,0);
        acch[mt][nt] = __builtin_amdgcn_mfma_f32_16x16x32_bf16(agl, bhh[nt], acch[mt][nt], 0,0,0);
      }
    }
  }
  __syncthreads();
#pragma unroll
  for (int mt=0; mt<4; ++mt){
#pragma unroll
    for (int nt=0; nt<2; ++nt){
#pragma unroll
      for (int r=0; r<4; ++r){
        const int rl = mt*16 + (lane>>4)*4 + r;
        const int c  = cbase + nt*16 + (lane&15);
        const int wid = s_wid[rl];
        const float z = sigm_(Xz[(size_t)wid*Hc + c] + accz[mt][nt][r]);
        const float p = tanhf(Xh[(size_t)wid*Hc + c] + acch[mt][nt][r]);
        const float shv = sumh[(size_t)(row0+rl)*Hc + c];
        const float nh = (1.0f - z)*shv + z*p;
        const int idx = s_idx[rl];
        if (idx < Mc) hout[(size_t)idx*Hc + c] = nh;
        lt[rl][c - col0] = nh;
      }
    }
  }
  if (do_repack){
    __syncthreads();
#pragma unroll
    for (int i=0;i<4;i++){
      const int q   = tid + i*256;
      const int tel = q>>8, tkl = (q>>6)&3, ln = q&63;
      const int row = tel*16 + (ln&15);
      const int cl0 = tkl*32 + (ln>>4)*8;
      u16x8 h8, l8;
#pragma unroll
      for (int j=0;j<8;j++){
        const float v = lt[row][cl0+j];
        const u16 a = f2bf(v);
        h8[j] = a; l8[j] = f2bf(v - bf2f(a));
      }
      const size_t off = ((size_t)((te0+tel)*16 + (col0>>5) + tkl)*64 + ln)*8;
      *(u16x8*)&HpH[off] = h8;
      *(u16x8*)&HpL[off] = l8;
    }
  }
}

// ---------------- u = h' @ Ur (split-bf16 MFMA, scatter epilogue) -----------
__global__ __launch_bounds__(256)
void k_gemm_u_mfma(const u16* __restrict__ HpH, const u16* __restrict__ HpL,
                   const u16* __restrict__ BrH, const u16* __restrict__ BrL,
                   const int* __restrict__ ids, float* __restrict__ u)
{
  __shared__ int s_idx[64];
  const int tid  = threadIdx.x;
  const int w    = tid>>6, lane = tid&63;
  const int row0 = blockIdx.x*64;
  const int col0 = blockIdx.y*128;
  if (tid < 64) s_idx[tid] = ids[row0 + tid];
  __syncthreads();
  f32x4 acc[4][2] = {};
  const int cbase = col0 + w*32;
  const int tn0   = cbase>>4;
  const int te0   = row0>>4;
  for (int kt=0; kt<16; ++kt){
    bf16x8 bh[2], bl[2];
#pragma unroll
    for (int nt=0; nt<2; ++nt){
      const size_t bo = ((size_t)((tn0+nt)*16 + kt)*64 + lane)*8;
      bh[nt] = *(const bf16x8*)&BrH[bo];
      bl[nt] = *(const bf16x8*)&BrL[bo];
    }
#pragma unroll
    for (int mt=0; mt<4; ++mt){
      const size_t ao = ((size_t)((te0+mt)*16 + kt)*64 + lane)*8;
      const bf16x8 ah = *(const bf16x8*)&HpH[ao];
      const bf16x8 al = *(const bf16x8*)&HpL[ao];
#pragma unroll
      for (int nt=0; nt<2; ++nt){
        acc[mt][nt] = __builtin_amdgcn_mfma_f32_16x16x32_bf16(ah, bh[nt], acc[mt][nt], 0,0,0);
        acc[mt][nt] = __builtin_amdgcn_mfma_f32_16x16x32_bf16(ah, bl[nt], acc[mt][nt], 0,0,0);
        acc[mt][nt] = __builtin_amdgcn_mfma_f32_16x16x32_bf16(al, bh[nt], acc[mt][nt], 0,0,0);
      }
    }
  }
#pragma unroll
  for (int mt=0; mt<4; ++mt){
#pragma unroll
    for (int nt=0; nt<2; ++nt){
#pragma unroll
      for (int r=0; r<4; ++r){
        const int rl = mt*16 + (lane>>4)*4 + r;
        const int c  = cbase + nt*16 + (lane&15);
        const int idx = s_idx[rl];
        if (idx < Mc) u[(size_t)idx*Hc + c] = acc[mt][nt][r];
      }
    }
  }
}

// ---------------- root gather + root GEMM (f32, tiny) -----------------------
__global__ __launch_bounds__(256)
void k_gather_root(const int* __restrict__ root_nei, const float* __restrict__ h,
                   float* __restrict__ sroot)
{
  const int b  = blockIdx.x*2 + (threadIdx.x>>7);
  const int c0 = (threadIdx.x&127)<<2;
  float4 s = make_float4(0.f,0.f,0.f,0.f);
#pragma unroll
  for (int kk=0; kk<NBc; kk++){
    const int j = root_nei[(size_t)b*NBc + kk];
    if (j >= Mc) break;
    const float4 hv = *(const float4*)&h[(size_t)j*Hc + c0];
    s.x+=hv.x; s.y+=hv.y; s.z+=hv.z; s.w+=hv.w;
  }
  *(float4*)&sroot[(size_t)b*Hc + c0] = s;
}

__global__ __launch_bounds__(256)
void k_gemm_root(const float* __restrict__ sroot, const float* __restrict__ Wn,
                 const float* __restrict__ Xw, const int* __restrict__ root_wid,
                 float* __restrict__ out)
{
  __shared__ float As[BKf][64];
  __shared__ float Bs[BKf][64];
  const int tid  = threadIdx.x;
  const int row0 = blockIdx.x*64, col0 = blockIdx.y*64;
  const int ty = tid>>4, tx = tid&15;
  float acc[4][4] = {};
  for (int kt=0; kt<Hc; kt+=BKf) {
#pragma unroll
    for (int i=0;i<2;i++){
      const int f  = tid + i*256;
      const int r  = f>>3, kg = f&7;
      const int gr = row0 + r;
      const float4 a4 = *(const float4*)&sroot[(size_t)gr*Hc + kt + kg*4];
      const float av_[4]={a4.x,a4.y,a4.z,a4.w};
#pragma unroll
      for (int j=0;j<4;j++){
        const int k = kg*4+j;
        As[k][r ^ ((k&7)<<2)] = av_[j];
      }
      const int kb = f>>4, cg = f&15;
      *(float4*)&Bs[kb][cg*4] = *(const float4*)&Wn[(size_t)(kt+kb)*Hc + col0 + cg*4];
    }
    __syncthreads();
#pragma unroll
    for (int k=0;k<BKf;k++){
      const float4 av = *(const float4*)&As[k][(ty*4) ^ ((k&7)<<2)];
      const float4 bv = *(const float4*)&Bs[k][tx*4];
      const float aa[4]={av.x,av.y,av.z,av.w}, bb[4]={bv.x,bv.y,bv.z,bv.w};
#pragma unroll
      for (int i2=0;i2<4;i2++)
#pragma unroll
        for (int j2=0;j2<4;j2++)
          acc[i2][j2] = fmaf(aa[i2], bb[j2], acc[i2][j2]);
    }
    __syncthreads();
  }
  const int gc0 = col0 + tx*4;
#pragma unroll
  for (int i=0;i<4;i++){
    const int gr  = row0 + ty*4 + i;
    const int wid = root_wid[gr];
    const float4 xw = *(const float4*)&Xw[(size_t)wid*Hc + gc0];
    float4 o;
    o.x = fmaxf(0.f, acc[i][0]+xw.x);
    o.y = fmaxf(0.f, acc[i][1]+xw.y);
    o.z = fmaxf(0.f, acc[i][2]+xw.z);
    o.w = fmaxf(0.f, acc[i][3]+xw.w);
    *(float4*)&out[(size_t)gr*Hc + gc0] = o;
  }
}

// ---------------------------------------------------------------------------
extern "C" void kernel_launch(void* const* d_in, const int* in_sizes, int n_in,
                              void* d_out, int out_size, void* d_ws, size_t ws_size,
                              hipStream_t stream)
{
  const int*   msg_wid  = (const int*)d_in[0];
  const int*   msg_nei  = (const int*)d_in[1];
  const int*   step_ids = (const int*)d_in[2];
  const int*   root_wid = (const int*)d_in[3];
  const int*   root_nei = (const int*)d_in[4];
  const float* emb  = (const float*)d_in[5];
  const float* Wz_w = (const float*)d_in[6];
  const float* Wz_b = (const float*)d_in[7];
  const float* Wr_w = (const float*)d_in[8];
  const float* Ur_w = (const float*)d_in[9];
  const float* Ur_b = (const float*)d_in[10];
  const float* Wh_w = (const float*)d_in[11];
  const float* Wh_b = (const float*)d_in[12];
  const float* W_w  = (const float*)d_in[13];
  const float* W_b  = (const float*)d_in[14];

  float* h    = (float*)d_out;                       // [M][H]
  float* rout = (float*)d_out + (size_t)Mc*Hc;       // [B][H]

  // ---- workspace layout ----
  constexpr size_t SZ_U    = (size_t)Mc*Hc*4;        // 176,160,768
  constexpr size_t SZ_SUMH = (size_t)CEc*Hc*4;       //  33,554,432
  constexpr size_t SZ_PK   = (size_t)CEc*Hc*2;       //  16,777,216 (x6)
  constexpr size_t SZ_X    = (size_t)Vc*Hc*4;        //   2,048,000 (x6: Xz..Xw,h0,u0)
  constexpr size_t SZ_BP   = (size_t)Hc*Hc*2;        //     524,288 (x6)
  constexpr size_t SZ_ROOT = (size_t)Bc*Hc*4;        //   1,048,576
  constexpr size_t NEED = SZ_U + SZ_SUMH + 6*SZ_PK + 6*SZ_X + 6*SZ_BP + SZ_ROOT;
  if (ws_size < NEED) return;   // 326.9 MB; fill evidence: ws ~531 MB

  char* p = (char*)d_ws;
  float* u    = (float*)p;  p += SZ_U;
  float* sumh = (float*)p;  p += SZ_SUMH;
  u16* AhH = (u16*)p; p += SZ_PK;
  u16* AhL = (u16*)p; p += SZ_PK;
  u16* AgH = (u16*)p; p += SZ_PK;
  u16* AgL = (u16*)p; p += SZ_PK;
  u16* HpH = (u16*)p; p += SZ_PK;
  u16* HpL = (u16*)p; p += SZ_PK;
  float* Xz = (float*)p; p += SZ_X;
  float* Xr = (float*)p; p += SZ_X;
  float* Xh = (float*)p; p += SZ_X;
  float* Xw = (float*)p; p += SZ_X;
  float* h0 = (float*)p; p += SZ_X;
  float* u0 = (float*)p; p += SZ_X;
  u16* BzH = (u16*)p; p += SZ_BP;
  u16* BzL = (u16*)p; p += SZ_BP;
  u16* BhH = (u16*)p; p += SZ_BP;
  u16* BhL = (u16*)p; p += SZ_BP;
  u16* BrH = (u16*)p; p += SZ_BP;
  u16* BrL = (u16*)p; p += SZ_BP;
  float* sroot = (float*)p;

  const dim3 blk(256);

  // ---- vocab tables (f32; biases folded; Xr carries Ur_b) ----
  const dim3 gx((Vc+63)/64, Hc/64);
  k_gemm_bias<<<gx, blk, 0, stream>>>(emb, Wz_w, Wz_b, Xz, Vc);
  k_gemm_bias<<<gx, blk, 0, stream>>>(emb, Wr_w, Ur_b, Xr, Vc);
  k_gemm_bias<<<gx, blk, 0, stream>>>(emb, Wh_w, Wh_b, Xh, Vc);
  k_gemm_bias<<<gx, blk, 0, stream>>>(emb, W_w,  W_b,  Xw, Vc);

  // ---- step-0 vocab tables: h0 = sig(Xz)*tanh(Xh); u0 = h0 @ Ur (f32) ----
  k_h0<<<dim3((Vc*Hc/4 + 255)/256), blk, 0, stream>>>(Xz, Xh, h0);
  k_gemm_plain<<<gx, blk, 0, stream>>>(h0, Ur_w, u0, Vc);

  // ---- pack recurrent weights into hi/lo MFMA fragments ----
  const float* Uz = Wz_w + (size_t)Hc*Hc;
  const float* Uh = Wh_w + (size_t)Hc*Hc;
  const float* Wn = W_w  + (size_t)Hc*Hc;
  k_pack_w<<<128, blk, 0, stream>>>(Uz,   BzH, BzL);
  k_pack_w<<<128, blk, 0, stream>>>(Uh,   BhH, BhL);
  k_pack_w<<<128, blk, 0, stream>>>(Ur_w, BrH, BrL);

  // ---- step 0: pure broadcast (sum_h == sum_gated == 0 for all leaves) ----
  static const int Esz[Tc] = {32768, 8192, 2048, 2048, 8192, 32768};
  k_bcast0<<<dim3(Esz[0]/2), blk, 0, stream>>>(step_ids, msg_wid, h0, u0, h, u);

  // ---- steps 1..5 (chunked at CE=16384 rows) ----
  for (int t=1; t<Tc; ++t){
    const int E = Esz[t];
    const int last = (t == Tc-1);
    for (int off=0; off<E; off+=CEc){
      const int CE = (E - off < CEc) ? (E - off) : CEc;
      const int* ids = step_ids + (size_t)t*EMAXc + off;
      k_gather_step<<<dim3(CE/2), blk, 0, stream>>>(ids, msg_nei, msg_wid,
                                                    h, u, Xr, sumh,
                                                    AhH, AhL, AgH, AgL);
      k_gemm_step_mfma<<<dim3(CE/64, 4), blk, 0, stream>>>(AhH, AhL, AgH, AgL,
                                                           sumh, BzH, BzL, BhH, BhL,
                                                           Xz, Xh, ids, msg_wid,
                                                           h, HpH, HpL, last ? 0 : 1);
      if (!last)
        k_gemm_u_mfma<<<dim3(CE/64, 4), blk, 0, stream>>>(HpH, HpL, BrH, BrL, ids, u);
    }
  }

  // ---- root aggregation (tiny) ----
  k_gather_root<<<dim3(Bc/2), blk, 0, stream>>>(root_nei, h, sroot);
  k_gemm_root<<<dim3(Bc/64, Hc/64), blk, 0, stream>>>(sroot, Wn, Xw, root_wid, rout);
}